// Round 12
// baseline (41.127 us; speedup 1.0000x reference)
//
#include <hip/hip_runtime.h>
#include <hip/hip_bf16.h>
#include <math.h>

// QuadraticNetCholesky fused kernel, round 12.
// y = x^T (L L^T) x = ||L^T x||^2 ; v_j = sum_{i>=j} x_i * c[i(i+1)/2 + j].
// R12: occupancy doubling. 256 threads / 64 samples (4 threads per sample),
// grid 2048 = 8 blocks/CU, launch_bounds(256,8) -> VGPR<=64 -> 32 waves/CU
// (was 16). Weight tables restored to d_ws prologue (R11 proved fold-in is
// -3us). Stage-3 c buffer is bf16 double-buffered [64][78]sh (39-word rows,
// coprime w/ 32 banks); 1 barrier per chunk. Consume split by j-mod-8 pairs
// {w,7-w,..}: 75 MACs/thread for every wave, v[6] only, full v_j per thread
// -> combine is 1 scalar/wave.

constexpr int NI  = 24;
constexpr int H1  = 128;
constexpr int H2  = 32;
constexpr int SPB = 64;      // samples per block (256 threads, 4 waves)
constexpr int NT_TOT = 19;   // ceil(300/16) W3 row tiles
constexpr int W3R = 304;
constexpr float LOG2E = 1.4426950408889634f;
constexpr float LN2SQ = 0.4804530139182014f;   // ln(2)^2

typedef __attribute__((ext_vector_type(8))) short bf16x8;
typedef __attribute__((ext_vector_type(4))) float f32x4;

struct TriMap { unsigned char i[320]; unsigned char j[320]; };
constexpr TriMap mk_map() {
    TriMap m{};
    int t = 0;
    for (int i = 0; i < NI; ++i)
        for (int j = 0; j <= i; ++j) { m.i[t] = (unsigned char)i; m.j[t] = (unsigned char)j; ++t; }
    for (; t < 320; ++t) { m.i[t] = 0; m.j[t] = 0; }
    return m;
}
constexpr TriMap TM = mk_map();

__device__ __forceinline__ float elu_f(float v) {
    return v > 0.0f ? v : __expf(v) - 1.0f;
}
__device__ __forceinline__ float exp2_hw(float x) {
    float r; asm("v_exp_f32 %0, %1" : "=v"(r) : "v"(x)); return r;
}
__device__ __forceinline__ float log2_hw(float x) {
    float r; asm("v_log_f32 %0, %1" : "=v"(r) : "v"(x)); return r;
}
// softplus(z)/ln2 with z' = z*log2e: max(z',0) + log2(1+2^-|z'|)  (proven)
__device__ __forceinline__ float softplus_g(float zp) {
    return fmaxf(zp, 0.0f) + log2_hw(1.0f + exp2_hw(-fabsf(zp)));
}
__device__ __forceinline__ unsigned short f2bf(float f) {
    return __builtin_bit_cast(unsigned short, __float2bfloat16(f));
}
__device__ __forceinline__ unsigned int pk2(float a, float b) {
    return (unsigned int)f2bf(a) | ((unsigned int)f2bf(b) << 16);
}
__device__ __forceinline__ bf16x8 cvt8(const float* __restrict__ p) {
    float4 a = *reinterpret_cast<const float4*>(p);
    float4 b = *reinterpret_cast<const float4*>(p + 4);
    uint4 u = make_uint4(pk2(a.x, a.y), pk2(a.z, a.w), pk2(b.x, b.y), pk2(b.z, b.w));
    return __builtin_bit_cast(bf16x8, u);
}

// ---- prologue: bf16 weight tables in d_ws (proven R7/R9 path) ----
// shorts: w1b [128][32] @0 (K-pad zeros); w2b [32][128] @4096;
//         w3b [304][32] @8192 (pre-scaled by log2e); b3s f32[304] @short 17920
//         (pre-scaled by log2e).
__global__ void wcvt(const float* __restrict__ W1, const float* __restrict__ W2,
                     const float* __restrict__ W3, const float* __restrict__ b3,
                     unsigned short* __restrict__ ws) {
    int idx = blockIdx.x * 256 + threadIdx.x;
    if (idx < 4096) {
        int n = idx >> 5, k = idx & 31;
        ws[idx] = f2bf(k < NI ? W1[n * NI + k] : 0.0f);
    } else if (idx < 8192) {
        ws[idx] = f2bf(W2[idx - 4096]);
    } else if (idx < 8192 + W3R * H2) {
        int j = idx - 8192;
        int t = j >> 5;
        ws[idx] = f2bf(t < 300 ? W3[j] * LOG2E : 0.0f);
    } else if (idx < 8192 + W3R * H2 + W3R) {
        int t = idx - (8192 + W3R * H2);
        float* b3s = reinterpret_cast<float*>(ws + 17920);
        b3s[t] = (t < 300) ? b3[t] * LOG2E : 0.0f;
    }
}

// j-slot for wave W: Jw = {j : j%8==W or j%8==7-W}, 6 values, slot 0..5.
// All indices below fold to constants after unroll (TM is constexpr).

// consume chunk CH for wave W: scan window t in [32CH, 32CH+32), pick own j.
template<int CH, int W>
__device__ __forceinline__ void consume4(const unsigned int* __restrict__ crow,
                                         const float xr[NI], float v[6]) {
    #pragma unroll
    for (int tl = 0; tl < 32; ++tl) {
        const int t = CH * 32 + tl;
        if (t < 300) {
            const int j = TM.j[t];
            if ((j & 7) == W || (j & 7) == (7 - W)) {
                const int slot = 2 * (j >> 3) + (((j & 7) == W) ? 0 : 1);
                unsigned int u = crow[(CH & 1) * 16 + (tl >> 1)];
                unsigned int bits = (tl & 1) ? (u & 0xffff0000u) : (u << 16);
                float cv = __builtin_bit_cast(float, bits);
                v[slot] = fmaf(xr[TM.i[t]], cv, v[slot]);
            }
        }
    }
}

__global__ __launch_bounds__(256, 8) void qnet_fused(
    const float* __restrict__ x,
    const unsigned short* __restrict__ w1b, const float* __restrict__ b1,
    const unsigned short* __restrict__ w2b, const float* __restrict__ b2,
    const unsigned short* __restrict__ w3b, const float* __restrict__ b3s,
    float* __restrict__ y, int B)
{
    // Layout (bytes): h2b [64][40]sh @0..5120 (live through stage 3);
    // h1s [64][40]sh @5120..10240 (stages 1-2, wave-private);
    // c_buf bf16 [64][78] @5120..15104 overlay (stage 3, dbuf 2x16 words);
    // vx f32 [64][4] @5120 overlay (final combine).
    __shared__ __align__(16) unsigned char L[15104];
    unsigned short* h2b = reinterpret_cast<unsigned short*>(L);
    unsigned short* h1s = reinterpret_cast<unsigned short*>(L + 5120);
    unsigned int*   cbw = reinterpret_cast<unsigned int*>(L + 5120);  // 39 words/row
    float*          vx  = reinterpret_cast<float*>(L + 5120);

    const int tid  = threadIdx.x;
    const int lane = tid & 63;               // == sample id for consume
    const int lr   = lane & 15, lq = lane >> 4;
    const int w    = __builtin_amdgcn_readfirstlane(tid >> 6);   // wave 0..3
    const size_t sbase = (size_t)blockIdx.x * SPB;

    // ---- x of own sample (consume side), fp32 regs ----
    float xr[NI];
    {
        const float4* xp4 = reinterpret_cast<const float4*>(x + (sbase + lane) * NI);
        #pragma unroll
        for (int q = 0; q < NI / 4; ++q) {
            float4 t4 = xp4[q];
            xr[4*q+0] = t4.x; xr[4*q+1] = t4.y; xr[4*q+2] = t4.z; xr[4*q+3] = t4.w;
        }
    }

    // ---- stage-1 B-frag: wave owns sample tile st=w (16 samples).
    // lq==3 is K-pad (w1b zero there) -> clamp pointer.
    const int srow = w * 16 + lr;            // own sample row (stages 1-2)
    bf16x8 xf = cvt8(x + (sbase + srow) * NI + (lq == 3 ? 0 : lq * 8));

    // ---- stages 1+2, K-chunked by 32; wave-private, no barriers ----
    f32x4 acc[2];
    acc[0] = (f32x4){0.f, 0.f, 0.f, 0.f};
    acc[1] = (f32x4){0.f, 0.f, 0.f, 0.f};

    #pragma unroll
    for (int kk = 0; kk < 4; ++kk) {
        #pragma unroll
        for (int n = 0; n < 2; ++n) {
            const int nt1 = 2 * kk + n;
            bf16x8 af = *reinterpret_cast<const bf16x8*>(w1b + (nt1 * 16 + lr) * 32 + lq * 8);
            const float4 bb1 = *reinterpret_cast<const float4*>(b1 + nt1 * 16 + 4 * lq);
            f32x4 a = {0.f, 0.f, 0.f, 0.f};
            a = __builtin_amdgcn_mfma_f32_16x16x32_bf16(af, xf, a, 0, 0, 0);
            // D: row(4lq+r)=h1 neuron, col(lr)=sample srow
            unsigned int p0 = pk2(elu_f(a[0] + bb1.x), elu_f(a[1] + bb1.y));
            unsigned int p1 = pk2(elu_f(a[2] + bb1.z), elu_f(a[3] + bb1.w));
            unsigned long long pw = (unsigned long long)p0 | ((unsigned long long)p1 << 32);
            *reinterpret_cast<unsigned long long*>(
                h1s + srow * 40 + n * 16 + 4 * lq) = pw;
        }
        bf16x8 hb = *reinterpret_cast<const bf16x8*>(h1s + srow * 40 + lq * 8);
        #pragma unroll
        for (int n2 = 0; n2 < 2; ++n2) {
            bf16x8 wf = *reinterpret_cast<const bf16x8*>(
                w2b + (n2 * 16 + lr) * H1 + kk * 32 + lq * 8);
            acc[n2] = __builtin_amdgcn_mfma_f32_16x16x32_bf16(wf, hb, acc[n2], 0, 0, 0);
        }
    }

    // ---- finish h2: elu + bias -> h2b (own rows) ----
    #pragma unroll
    for (int n2 = 0; n2 < 2; ++n2) {
        const float4 bb2 = *reinterpret_cast<const float4*>(b2 + n2 * 16 + 4 * lq);
        unsigned int p0 = pk2(elu_f(acc[n2][0] + bb2.x), elu_f(acc[n2][1] + bb2.y));
        unsigned int p1 = pk2(elu_f(acc[n2][2] + bb2.z), elu_f(acc[n2][3] + bb2.w));
        unsigned long long pw = (unsigned long long)p0 | ((unsigned long long)p1 << 32);
        *reinterpret_cast<unsigned long long*>(
            h2b + srow * 40 + n2 * 16 + 4 * lq) = pw;
    }
    __syncthreads();   // h2b ready for all waves; h1s dead -> c_buf region

    // ---- stage 3: 10 chunks of 32 t; produce (2 MFMA/wave) -> barrier ->
    // consume (own j-set, ~7-8 t). One barrier per chunk (dbuf c_buf).
    float v[6];
    #pragma unroll
    for (int q = 0; q < 6; ++q) v[q] = 0.f;

    const int nt_off = w >> 1;               // which 16-t tile of the chunk
    const int st0 = 2 * (w & 1);             // which sample-tile pair

#define QNET_CHUNK(CH)                                                         \
    {                                                                          \
        const int my_nt = 2 * (CH) + nt_off;                                   \
        if (my_nt < NT_TOT) {                                                  \
            bf16x8 af = *reinterpret_cast<const bf16x8*>(                      \
                w3b + (my_nt * 16 + lr) * H2 + lq * 8);                        \
            const float4 b4 = *reinterpret_cast<const float4*>(                \
                b3s + my_nt * 16 + 4 * lq);                                    \
            _Pragma("unroll")                                                  \
            for (int u = 0; u < 2; ++u) {                                      \
                const int st = st0 + u;                                        \
                bf16x8 hb = *reinterpret_cast<const bf16x8*>(                  \
                    h2b + (st * 16 + lr) * 40 + lq * 8);                       \
                f32x4 a = {0.f, 0.f, 0.f, 0.f};                                \
                a = __builtin_amdgcn_mfma_f32_16x16x32_bf16(af, hb, a, 0, 0, 0);\
                float s0 = softplus_g(a[0] + b4.x);                            \
                float s1 = softplus_g(a[1] + b4.y);                            \
                float s2 = softplus_g(a[2] + b4.z);                            \
                float s3 = softplus_g(a[3] + b4.w);                            \
                const int word = (st * 16 + lr) * 39 + ((CH) & 1) * 16         \
                                 + nt_off * 8 + 2 * lq;                        \
                cbw[word]     = pk2(s0, s1);                                   \
                cbw[word + 1] = pk2(s2, s3);                                   \
            }                                                                  \
        }                                                                      \
        __syncthreads();                                                       \
        const unsigned int* crow = cbw + lane * 39;                            \
        if      (w == 0) consume4<(CH), 0>(crow, xr, v);                       \
        else if (w == 1) consume4<(CH), 1>(crow, xr, v);                       \
        else if (w == 2) consume4<(CH), 2>(crow, xr, v);                       \
        else             consume4<(CH), 3>(crow, xr, v);                       \
    }

    QNET_CHUNK(0) QNET_CHUNK(1) QNET_CHUNK(2) QNET_CHUNK(3) QNET_CHUNK(4)
    QNET_CHUNK(5) QNET_CHUNK(6) QNET_CHUNK(7) QNET_CHUNK(8) QNET_CHUNK(9)
#undef QNET_CHUNK

    // ---- each thread has FULL v_j for its 6 j -> partial y scalar ----
    float py = 0.f;
    #pragma unroll
    for (int q = 0; q < 6; ++q) py = fmaf(v[q], v[q], py);

    __syncthreads();   // all consumes done; c_buf dead -> vx overlay
    if (w > 0) vx[lane * 4 + (w - 1)] = py;
    __syncthreads();
    if (w == 0) {
        float tot = py + vx[lane * 4 + 0] + vx[lane * 4 + 1] + vx[lane * 4 + 2];
        y[sbase + lane] = LN2SQ * tot;
    }
}

extern "C" void kernel_launch(void* const* d_in, const int* in_sizes, int n_in,
                              void* d_out, int out_size, void* d_ws, size_t ws_size,
                              hipStream_t stream) {
    const float* x  = (const float*)d_in[0];
    const float* W1 = (const float*)d_in[1];
    const float* b1 = (const float*)d_in[2];
    const float* W2 = (const float*)d_in[3];
    const float* b2 = (const float*)d_in[4];
    const float* W3 = (const float*)d_in[5];
    const float* b3 = (const float*)d_in[6];
    float* y = (float*)d_out;

    unsigned short* ws = (unsigned short*)d_ws;      // 37056 B used
    const unsigned short* w1b = ws;
    const unsigned short* w2b = ws + 4096;
    const unsigned short* w3b = ws + 8192;
    const float* b3s = reinterpret_cast<const float*>(ws + 17920);

    const int B = in_sizes[0] / NI;   // 131072, divisible by SPB
    const int cvt_elems = 8192 + W3R * H2 + W3R;
    wcvt<<<dim3((cvt_elems + 255) / 256), dim3(256), 0, stream>>>(W1, W2, W3, b3, ws);
    qnet_fused<<<dim3(B / SPB), dim3(256), 0, stream>>>(
        x, w1b, b1, w2b, b2, w3b, b3s, y, B);
}

// Round 13
// 38.679 us; speedup vs baseline: 1.0633x; 1.0633x over previous
//
#include <hip/hip_runtime.h>
#include <hip/hip_bf16.h>
#include <math.h>

// QuadraticNetCholesky fused kernel, round 13.
// y = x^T (L L^T) x = ||L^T x||^2 ; v_j = sum_{i>=j} x_i * c[i(i+1)/2 + j].
// R13: clean 32-waves/CU occupancy test (R12 retry with its defects fixed):
//  - x lives in LDS (xs[64][25] f32) -> no xr[24] in regs -> VGPR ~45 <= 64
//    (the 8-waves/SIMD cliff). launch_bounds(256,8).
//  - c_buf f32 stride-34 (2-way bank = free), f32x2 stores, plain f32 consume.
//  - j mod 4 wave split: v[6]/thread, full v_j per thread.
//  - LDS 20224 B -> 8 blocks/CU x 4 waves = 32 waves/CU, grid 2048 = no tail.

constexpr int NI  = 24;
constexpr int H1  = 128;
constexpr int H2  = 32;
constexpr int SPB = 64;      // samples per block (256 threads, 4 waves)
constexpr int NT_TOT = 19;   // ceil(300/16) W3 row tiles
constexpr int W3R = 304;
constexpr float LOG2E = 1.4426950408889634f;
constexpr float LN2SQ = 0.4804530139182014f;   // ln(2)^2

typedef __attribute__((ext_vector_type(8))) short bf16x8;
typedef __attribute__((ext_vector_type(2))) float f32x2;
typedef __attribute__((ext_vector_type(4))) float f32x4;

struct TriMap { unsigned char i[320]; unsigned char j[320]; };
constexpr TriMap mk_map() {
    TriMap m{};
    int t = 0;
    for (int i = 0; i < NI; ++i)
        for (int j = 0; j <= i; ++j) { m.i[t] = (unsigned char)i; m.j[t] = (unsigned char)j; ++t; }
    for (; t < 320; ++t) { m.i[t] = 0; m.j[t] = 0; }
    return m;
}
constexpr TriMap TM = mk_map();

__device__ __forceinline__ float elu_f(float v) {
    return v > 0.0f ? v : __expf(v) - 1.0f;
}
__device__ __forceinline__ float exp2_hw(float x) {
    float r; asm("v_exp_f32 %0, %1" : "=v"(r) : "v"(x)); return r;
}
__device__ __forceinline__ float log2_hw(float x) {
    float r; asm("v_log_f32 %0, %1" : "=v"(r) : "v"(x)); return r;
}
// softplus(z)/ln2 with z' = z*log2e: max(z',0) + log2(1+2^-|z'|)  (proven)
__device__ __forceinline__ float softplus_g(float zp) {
    return fmaxf(zp, 0.0f) + log2_hw(1.0f + exp2_hw(-fabsf(zp)));
}
__device__ __forceinline__ unsigned short f2bf(float f) {
    return __builtin_bit_cast(unsigned short, __float2bfloat16(f));
}
__device__ __forceinline__ unsigned int pk2(float a, float b) {
    return (unsigned int)f2bf(a) | ((unsigned int)f2bf(b) << 16);
}
__device__ __forceinline__ bf16x8 cvt8(const float* __restrict__ p) {
    float4 a = *reinterpret_cast<const float4*>(p);
    float4 b = *reinterpret_cast<const float4*>(p + 4);
    uint4 u = make_uint4(pk2(a.x, a.y), pk2(a.z, a.w), pk2(b.x, b.y), pk2(b.z, b.w));
    return __builtin_bit_cast(bf16x8, u);
}

// ---- prologue: bf16 weight tables in d_ws (proven path) ----
// shorts: w1b [128][32] @0 (K-pad zeros); w2b [32][128] @4096;
//         w3b [304][32] @8192 (pre-scaled log2e); b3s f32[304] @short 17920.
__global__ void wcvt(const float* __restrict__ W1, const float* __restrict__ W2,
                     const float* __restrict__ W3, const float* __restrict__ b3,
                     unsigned short* __restrict__ ws) {
    int idx = blockIdx.x * 256 + threadIdx.x;
    if (idx < 4096) {
        int n = idx >> 5, k = idx & 31;
        ws[idx] = f2bf(k < NI ? W1[n * NI + k] : 0.0f);
    } else if (idx < 8192) {
        ws[idx] = f2bf(W2[idx - 4096]);
    } else if (idx < 8192 + W3R * H2) {
        int j = idx - 8192;
        int t = j >> 5;
        ws[idx] = f2bf(t < 300 ? W3[j] * LOG2E : 0.0f);
    } else if (idx < 8192 + W3R * H2 + W3R) {
        int t = idx - (8192 + W3R * H2);
        float* b3s = reinterpret_cast<float*>(ws + 17920);
        b3s[t] = (t < 300) ? b3[t] * LOG2E : 0.0f;
    }
}

// consume chunk CH for wave W (j%4==W): static t->(i,j) mapping, f32 reads.
template<int CH, int W>
__device__ __forceinline__ void consume5(const float* __restrict__ crow,
                                         const float* __restrict__ xrow,
                                         float v[6]) {
    #pragma unroll
    for (int tl = 0; tl < 32; ++tl) {
        const int t = CH * 32 + tl;
        if (t < 300 && (TM.j[t] & 3) == W)
            v[TM.j[t] >> 2] = fmaf(xrow[TM.i[t]], crow[tl], v[TM.j[t] >> 2]);
    }
}

__global__ __launch_bounds__(256, 8) void qnet_fused(
    const float* __restrict__ x,
    const unsigned short* __restrict__ w1b, const float* __restrict__ b1,
    const unsigned short* __restrict__ w2b, const float* __restrict__ b2,
    const unsigned short* __restrict__ w3b, const float* __restrict__ b3s,
    float* __restrict__ y, int B)
{
    // Layout (bytes): xs f32[64][25] @0..6400 (live whole kernel);
    // h2b sh[64][40] @6400..11520 (stage2 -> stage3 end);
    // h1s sh[64][40] @11520..16640 (stages 1-2 only);
    // c_buf f32[64][34] @11520..20224 (stage 3, overlays h1s);
    // vx f32[64][3] @11520 (final, overlays c_buf). Total 20224 B.
    __shared__ __align__(16) unsigned char L[20224];
    float*          xs  = reinterpret_cast<float*>(L);
    unsigned short* h2b = reinterpret_cast<unsigned short*>(L + 6400);
    unsigned short* h1s = reinterpret_cast<unsigned short*>(L + 11520);
    float*          cb  = reinterpret_cast<float*>(L + 11520);
    float*          vx  = reinterpret_cast<float*>(L + 11520);

    const int tid  = threadIdx.x;
    const int lane = tid & 63;               // == sample id for consume
    const int lr   = lane & 15, lq = lane >> 4;
    const int w    = __builtin_amdgcn_readfirstlane(tid >> 6);   // wave 0..3
    const size_t sbase = (size_t)blockIdx.x * SPB;

    // ---- fill xs: thread (w,lane) writes xs[lane][6w..6w+6) (f32x2 x3) ----
    {
        const float* xp = x + (sbase + lane) * NI + 6 * w;
        f32x2 a = *reinterpret_cast<const f32x2*>(xp);
        f32x2 b = *reinterpret_cast<const f32x2*>(xp + 2);
        f32x2 c = *reinterpret_cast<const f32x2*>(xp + 4);
        float* dst = xs + lane * 25 + 6 * w;
        dst[0] = a[0]; dst[1] = a[1]; dst[2] = b[0];
        dst[3] = b[1]; dst[4] = c[0]; dst[5] = c[1];
    }

    // ---- stage-1 B-frag: wave owns sample tile st=w. lq==3 is K-pad. ----
    const int srow = w * 16 + lr;            // own sample row (stages 1-2)
    bf16x8 xf = cvt8(x + (sbase + srow) * NI + (lq == 3 ? 0 : lq * 8));

    // ---- stages 1+2, K-chunked by 32; wave-private, no barriers ----
    f32x4 acc[2];
    acc[0] = (f32x4){0.f, 0.f, 0.f, 0.f};
    acc[1] = (f32x4){0.f, 0.f, 0.f, 0.f};

    #pragma unroll
    for (int kk = 0; kk < 4; ++kk) {
        #pragma unroll
        for (int n = 0; n < 2; ++n) {
            const int nt1 = 2 * kk + n;
            bf16x8 af = *reinterpret_cast<const bf16x8*>(w1b + (nt1 * 16 + lr) * 32 + lq * 8);
            const float4 bb1 = *reinterpret_cast<const float4*>(b1 + nt1 * 16 + 4 * lq);
            f32x4 a = {0.f, 0.f, 0.f, 0.f};
            a = __builtin_amdgcn_mfma_f32_16x16x32_bf16(af, xf, a, 0, 0, 0);
            unsigned int p0 = pk2(elu_f(a[0] + bb1.x), elu_f(a[1] + bb1.y));
            unsigned int p1 = pk2(elu_f(a[2] + bb1.z), elu_f(a[3] + bb1.w));
            unsigned long long pw = (unsigned long long)p0 | ((unsigned long long)p1 << 32);
            *reinterpret_cast<unsigned long long*>(
                h1s + srow * 40 + n * 16 + 4 * lq) = pw;
        }
        bf16x8 hb = *reinterpret_cast<const bf16x8*>(h1s + srow * 40 + lq * 8);
        #pragma unroll
        for (int n2 = 0; n2 < 2; ++n2) {
            bf16x8 wf = *reinterpret_cast<const bf16x8*>(
                w2b + (n2 * 16 + lr) * H1 + kk * 32 + lq * 8);
            acc[n2] = __builtin_amdgcn_mfma_f32_16x16x32_bf16(wf, hb, acc[n2], 0, 0, 0);
        }
    }

    // ---- finish h2: elu + bias -> h2b (own rows) ----
    #pragma unroll
    for (int n2 = 0; n2 < 2; ++n2) {
        const float4 bb2 = *reinterpret_cast<const float4*>(b2 + n2 * 16 + 4 * lq);
        unsigned int p0 = pk2(elu_f(acc[n2][0] + bb2.x), elu_f(acc[n2][1] + bb2.y));
        unsigned int p1 = pk2(elu_f(acc[n2][2] + bb2.z), elu_f(acc[n2][3] + bb2.w));
        unsigned long long pw = (unsigned long long)p0 | ((unsigned long long)p1 << 32);
        *reinterpret_cast<unsigned long long*>(
            h2b + srow * 40 + n2 * 16 + 4 * lq) = pw;
    }
    __syncthreads();   // h2b (and xs) visible to all; h1s dead -> c_buf

    // ---- stage 3: 10 chunks; produce 2 MFMA/wave -> barrier -> consume
    // own j%4 set -> barrier (c_buf single-buffered cols 0..31).
    float v[6];
    #pragma unroll
    for (int q = 0; q < 6; ++q) v[q] = 0.f;

    const int nt_off = w >> 1;               // which nt of the chunk pair
    const int st0 = 2 * (w & 1);             // which sample-tile pair

#define QNET_CHUNK(CH)                                                         \
    {                                                                          \
        const int my_nt = 2 * (CH) + nt_off;                                   \
        if (my_nt < NT_TOT) {                                                  \
            bf16x8 af = *reinterpret_cast<const bf16x8*>(                      \
                w3b + (my_nt * 16 + lr) * H2 + lq * 8);                        \
            const float4 b4 = *reinterpret_cast<const float4*>(                \
                b3s + my_nt * 16 + 4 * lq);                                    \
            _Pragma("unroll")                                                  \
            for (int u = 0; u < 2; ++u) {                                      \
                const int st = st0 + u;                                        \
                bf16x8 hb = *reinterpret_cast<const bf16x8*>(                  \
                    h2b + (st * 16 + lr) * 40 + lq * 8);                       \
                f32x4 a = {0.f, 0.f, 0.f, 0.f};                                \
                a = __builtin_amdgcn_mfma_f32_16x16x32_bf16(af, hb, a, 0, 0, 0);\
                /* D: row(4lq+r)=t-in-tile, col(lr)=sample-in-st-tile */       \
                f32x2 w0, w1;                                                  \
                w0[0] = softplus_g(a[0] + b4.x);                               \
                w0[1] = softplus_g(a[1] + b4.y);                               \
                w1[0] = softplus_g(a[2] + b4.z);                               \
                w1[1] = softplus_g(a[3] + b4.w);                               \
                float* dst = cb + (st * 16 + lr) * 34 + nt_off * 16 + 4 * lq;  \
                *reinterpret_cast<f32x2*>(dst)     = w0;                       \
                *reinterpret_cast<f32x2*>(dst + 2) = w1;                       \
            }                                                                  \
        }                                                                      \
        __syncthreads();                                                       \
        {                                                                      \
            const float* crow = cb + lane * 34;                                \
            const float* xrow = xs + lane * 25;                                \
            if      (w == 0) consume5<(CH), 0>(crow, xrow, v);                 \
            else if (w == 1) consume5<(CH), 1>(crow, xrow, v);                 \
            else if (w == 2) consume5<(CH), 2>(crow, xrow, v);                 \
            else             consume5<(CH), 3>(crow, xrow, v);                 \
        }                                                                      \
        __syncthreads();                                                       \
    }

    QNET_CHUNK(0) QNET_CHUNK(1) QNET_CHUNK(2) QNET_CHUNK(3) QNET_CHUNK(4)
    QNET_CHUNK(5) QNET_CHUNK(6) QNET_CHUNK(7) QNET_CHUNK(8) QNET_CHUNK(9)
#undef QNET_CHUNK

    // ---- each thread has FULL v_j for its 6 j (j%4==w) -> partial y ----
    float py = 0.f;
    #pragma unroll
    for (int q = 0; q < 6; ++q) py = fmaf(v[q], v[q], py);

    // c_buf dead (trailing chunk-9 barrier passed) -> vx overlay
    if (w > 0) vx[lane * 3 + (w - 1)] = py;
    __syncthreads();
    if (w == 0) {
        float tot = py + vx[lane * 3 + 0] + vx[lane * 3 + 1] + vx[lane * 3 + 2];
        y[sbase + lane] = LN2SQ * tot;
    }
}

extern "C" void kernel_launch(void* const* d_in, const int* in_sizes, int n_in,
                              void* d_out, int out_size, void* d_ws, size_t ws_size,
                              hipStream_t stream) {
    const float* x  = (const float*)d_in[0];
    const float* W1 = (const float*)d_in[1];
    const float* b1 = (const float*)d_in[2];
    const float* W2 = (const float*)d_in[3];
    const float* b2 = (const float*)d_in[4];
    const float* W3 = (const float*)d_in[5];
    const float* b3 = (const float*)d_in[6];
    float* y = (float*)d_out;

    unsigned short* ws = (unsigned short*)d_ws;      // 37056 B used
    const unsigned short* w1b = ws;
    const unsigned short* w2b = ws + 4096;
    const unsigned short* w3b = ws + 8192;
    const float* b3s = reinterpret_cast<const float*>(ws + 17920);

    const int B = in_sizes[0] / NI;   // 131072, divisible by SPB
    const int cvt_elems = 8192 + W3R * H2 + W3R;
    wcvt<<<dim3((cvt_elems + 255) / 256), dim3(256), 0, stream>>>(W1, W2, W3, b3, ws);
    qnet_fused<<<dim3(B / SPB), dim3(256), 0, stream>>>(
        x, w1b, b1, w2b, b2, w3b, b3s, y, B);
}

// Round 14
// 35.553 us; speedup vs baseline: 1.1568x; 1.0879x over previous
//
#include <hip/hip_runtime.h>
#include <hip/hip_bf16.h>
#include <math.h>

// QuadraticNetCholesky fused kernel, round 14 == round 7 (best measured:
// 35.7 us). y = x^T (L L^T) x = ||L^T x||^2 ; v_j = sum_{i>=j} x_i * c[t(i,j)].
// All three matmuls on MFMA 16x16x32 bf16; bf16 weight tables in d_ws
// (wcvt prologue; R11 measured folding it in = -3us regression); softplus
// exp2-folded (W3,b3 pre-scaled by log2e, y scaled by ln2^2); stage-3
// j-parity split with register-resident x.
// Rounds 8-13 tested: LDS-vectorized consume (R8, -3us), barrier elimination
// (R9, -1.8us), kernel fusion (R11, -5us), 32-waves/CU occupancy (R12/R13,
// -3..-5us). All regressions -> this configuration is the empirical optimum;
// remaining gap to the ~20-25us perfect-overlap bound is multi-pipe
// (VALU/trans/LDS) contention that no tested rearrangement improves.

constexpr int NI  = 24;
constexpr int H1  = 128;
constexpr int H2  = 32;
constexpr int SPB = 128;     // samples per block (256 threads, 4 waves)
constexpr int NT_TOT = 19;   // ceil(300/16) W3 row tiles
constexpr int W3R = 304;
constexpr float LOG2E = 1.4426950408889634f;
constexpr float LN2SQ = 0.4804530139182014f;   // ln(2)^2

typedef __attribute__((ext_vector_type(8))) short bf16x8;
typedef __attribute__((ext_vector_type(4))) float f32x4;

__device__ __forceinline__ float elu_f(float v) {
    return v > 0.0f ? v : __expf(v) - 1.0f;
}
__device__ __forceinline__ float exp2_hw(float x) {
    float r; asm("v_exp_f32 %0, %1" : "=v"(r) : "v"(x)); return r;
}
__device__ __forceinline__ float log2_hw(float x) {
    float r; asm("v_log_f32 %0, %1" : "=v"(r) : "v"(x)); return r;
}
// softplus(z)/ln2 with z' = z*log2e as input: max(z',0) + log2(1+2^-|z'|)
__device__ __forceinline__ float softplus_g(float zp) {
    return fmaxf(zp, 0.0f) + log2_hw(1.0f + exp2_hw(-fabsf(zp)));
}
__device__ __forceinline__ unsigned short f2bf(float f) {
    return __builtin_bit_cast(unsigned short, __float2bfloat16(f));
}
__device__ __forceinline__ unsigned int pk2(float a, float b) {
    return (unsigned int)f2bf(a) | ((unsigned int)f2bf(b) << 16);
}

// ---- prologue: bf16 weight tables in d_ws ----
// shorts: w1b [128][32] @0 (K-pad 24->32 zeros); w2b [32][128] @4096;
//         w3b [304][32] @8192 (pre-scaled by log2e); b3s f32[304] @short 17920.
__global__ void wcvt(const float* __restrict__ W1, const float* __restrict__ W2,
                     const float* __restrict__ W3, const float* __restrict__ b3,
                     unsigned short* __restrict__ ws) {
    int idx = blockIdx.x * 256 + threadIdx.x;
    if (idx < 4096) {
        int n = idx >> 5, k = idx & 31;
        ws[idx] = f2bf(k < NI ? W1[n * NI + k] : 0.0f);
    } else if (idx < 8192) {
        ws[idx] = f2bf(W2[idx - 4096]);
    } else if (idx < 8192 + W3R * H2) {
        int j = idx - 8192;
        int t = j >> 5;
        ws[idx] = f2bf(t < 300 ? W3[j] * LOG2E : 0.0f);
    } else if (idx < 8192 + W3R * H2 + W3R) {
        int t = idx - (8192 + W3R * H2);
        float* b3s = reinterpret_cast<float*>(ws + 17920);
        b3s[t] = (t < 300) ? b3[t] * LOG2E : 0.0f;
    }
}

// compile-time-pruned v accumulation over window [C0, C0+32)
template<int J0, int C0>
__device__ __forceinline__ void vaccum(const float xr[NI], float v[12],
                                       const float* __restrict__ crow) {
    #pragma unroll
    for (int q = 0; q < 12; ++q) {
        const int j = 2 * q + J0;
        #pragma unroll
        for (int i = j; i < NI; ++i) {
            const int t = i * (i + 1) / 2 + j;
            if (t >= C0 && t < C0 + 32)
                v[q] = fmaf(xr[i], crow[t - C0], v[q]);
        }
    }
}

template<int CH>
__device__ __forceinline__ void chunk_body(
    int w_hi, int w_lo, int lr, int lq, int sid, int half,
    const unsigned short* __restrict__ w3b, const float* __restrict__ b3s,
    const float xr[NI], float v[12],
    float* __restrict__ c_buf, const unsigned short* __restrict__ h2b)
{
    const int my_nt = 2 * CH + w_hi;          // wave-uniform N-tile
    if (my_nt < NT_TOT) {
        const int t = my_nt * 16 + lr;
        bf16x8 wf = *reinterpret_cast<const bf16x8*>(w3b + t * H2 + lq * 8);
        const float bias = b3s[t];
        #pragma unroll
        for (int q = 0; q < 4; ++q) {
            const int st = 4 * w_lo + q;
            bf16x8 hb = *reinterpret_cast<const bf16x8*>(h2b + (st * 16 + lr) * 40 + lq * 8);
            f32x4 a = {0.f, 0.f, 0.f, 0.f};
            a = __builtin_amdgcn_mfma_f32_16x16x32_bf16(hb, wf, a, 0, 0, 0);
            // C: col(lane&15)=t-in-tile, row(4lq+r)=sample-in-st-tile
            #pragma unroll
            for (int r = 0; r < 4; ++r) {
                float g = softplus_g(a[r] + bias);
                c_buf[(st * 16 + 4 * lq + r) * 33 + (my_nt & 1) * 16 + lr] = g;
            }
        }
    }
    __syncthreads();
    if (half == 0) vaccum<1, CH * 32>(xr, v, c_buf + sid * 33);   // odd j
    else           vaccum<0, CH * 32>(xr, v, c_buf + sid * 33);   // even j
    __syncthreads();
}

__global__ __launch_bounds__(256, 4) void qnet_fused(
    const float* __restrict__ x,
    const unsigned short* __restrict__ w1b, const float* __restrict__ b1,
    const unsigned short* __restrict__ w2b, const float* __restrict__ b2,
    const unsigned short* __restrict__ w3b, const float* __restrict__ b3s,
    float* __restrict__ y, int B)
{
    // Layout (bytes): xb [128][40]sh @0..10240 ; h1s [128][40]sh @10240..20480 ;
    // h2b [128][40]sh @20480..30720 ; overlays on dead xb+h1s after stage 2:
    // c_buf [128][33]f32 @0..16896 ; yb f32[128] @16896..17408.
    __shared__ __align__(16) unsigned char L[30720];
    unsigned short* xb  = reinterpret_cast<unsigned short*>(L);          // [128][40]
    unsigned short* h1s = reinterpret_cast<unsigned short*>(L + 10240);  // [128][40]
    unsigned short* h2b = reinterpret_cast<unsigned short*>(L + 20480);  // [128][40]
    float* c_buf = reinterpret_cast<float*>(L);                          // [128][33] overlay
    float* yb    = reinterpret_cast<float*>(L + 16896);                  // [128] overlay

    const int tid  = threadIdx.x;
    const int sid  = tid & (SPB - 1);
    const int lane = tid & 63;
    const int lr   = lane & 15, lq = lane >> 4;
    const int half = __builtin_amdgcn_readfirstlane(tid >> 7);
    const int wid  = __builtin_amdgcn_readfirstlane(tid >> 6);
    const int w_hi = wid >> 1, w_lo = wid & 1;
    const size_t sbase = (size_t)blockIdx.x * SPB;

    // ---- x: fp32 in regs (for quadratic form) + bf16 once into xb ----
    float xr[NI];
    {
        const float4* xp4 = reinterpret_cast<const float4*>(x + (sbase + sid) * NI);
        #pragma unroll
        for (int q = 0; q < NI / 4; ++q) {
            float4 t4 = xp4[q];
            xr[4*q+0] = t4.x; xr[4*q+1] = t4.y; xr[4*q+2] = t4.z; xr[4*q+3] = t4.w;
        }
    }
    if (half == 0) {
        unsigned int pk[12];
        #pragma unroll
        for (int q = 0; q < 12; ++q) pk[q] = pk2(xr[2*q], xr[2*q+1]);
        uint4* dst = reinterpret_cast<uint4*>(xb + sid * 40);
        dst[0] = make_uint4(pk[0], pk[1], pk[2], pk[3]);
        dst[1] = make_uint4(pk[4], pk[5], pk[6], pk[7]);
        dst[2] = make_uint4(pk[8], pk[9], pk[10], pk[11]);
    } else {
        *reinterpret_cast<uint4*>(xb + sid * 40 + 24) = make_uint4(0, 0, 0, 0);  // K-pad
    }
    __syncthreads();

    // ---- stages 1+2, K-chunked by 32 h1-rows; stage-2 partials in regs ----
    f32x4 acc[2][2];
    #pragma unroll
    for (int u = 0; u < 2; ++u)
        #pragma unroll
        for (int n2 = 0; n2 < 2; ++n2) acc[u][n2] = (f32x4){0.f, 0.f, 0.f, 0.f};

    #pragma unroll
    for (int kk = 0; kk < 4; ++kk) {
        // stage 1: h1 rows [32kk, 32kk+32) for all 128 samples
        const int nt1 = 2 * kk + w_hi;
        bf16x8 af = *reinterpret_cast<const bf16x8*>(w1b + (nt1 * 16 + lr) * 32 + lq * 8);
        const float4 bb1 = *reinterpret_cast<const float4*>(b1 + nt1 * 16 + 4 * lq);
        #pragma unroll
        for (int q = 0; q < 4; ++q) {
            const int st = 4 * w_lo + q;
            bf16x8 bf = *reinterpret_cast<const bf16x8*>(xb + (st * 16 + lr) * 40 + lq * 8);
            f32x4 a = {0.f, 0.f, 0.f, 0.f};
            a = __builtin_amdgcn_mfma_f32_16x16x32_bf16(af, bf, a, 0, 0, 0);
            unsigned int p0 = pk2(elu_f(a[0] + bb1.x), elu_f(a[1] + bb1.y));
            unsigned int p1 = pk2(elu_f(a[2] + bb1.z), elu_f(a[3] + bb1.w));
            unsigned long long pw = (unsigned long long)p0 | ((unsigned long long)p1 << 32);
            // sample = st*16+lr; local col = w_hi*16 + 4lq + r
            *reinterpret_cast<unsigned long long*>(
                h1s + (st * 16 + lr) * 40 + w_hi * 16 + 4 * lq) = pw;
        }
        __syncthreads();
        // stage 2: accumulate this K-chunk into register C-tiles
        #pragma unroll
        for (int u = 0; u < 2; ++u) {
            const int st2 = 2 * wid + u;
            bf16x8 hb = *reinterpret_cast<const bf16x8*>(h1s + (st2 * 16 + lr) * 40 + lq * 8);
            #pragma unroll
            for (int n2 = 0; n2 < 2; ++n2) {
                bf16x8 wf = *reinterpret_cast<const bf16x8*>(
                    w2b + (n2 * 16 + lr) * H1 + kk * 32 + lq * 8);
                acc[u][n2] = __builtin_amdgcn_mfma_f32_16x16x32_bf16(wf, hb, acc[u][n2], 0, 0, 0);
            }
        }
        __syncthreads();
    }

    // ---- finish h2: elu + bias, pack bf16 to h2b ----
    #pragma unroll
    for (int u = 0; u < 2; ++u) {
        const int st2 = 2 * wid + u;
        #pragma unroll
        for (int n2 = 0; n2 < 2; ++n2) {
            const float4 bb2 = *reinterpret_cast<const float4*>(b2 + n2 * 16 + 4 * lq);
            unsigned int p0 = pk2(elu_f(acc[u][n2][0] + bb2.x), elu_f(acc[u][n2][1] + bb2.y));
            unsigned int p1 = pk2(elu_f(acc[u][n2][2] + bb2.z), elu_f(acc[u][n2][3] + bb2.w));
            unsigned long long pw = (unsigned long long)p0 | ((unsigned long long)p1 << 32);
            // sample = st2*16+lr; col = n2*16 + 4lq + r
            *reinterpret_cast<unsigned long long*>(
                h2b + (st2 * 16 + lr) * 40 + n2 * 16 + 4 * lq) = pw;
        }
    }
    __syncthreads();   // h2b ready; xb/h1s dead -> region becomes c_buf

    // ---- stage 3: 10 chunks of 32 tril-cols ----
    float v[12];
    #pragma unroll
    for (int q = 0; q < 12; ++q) v[q] = 0.f;

    chunk_body<0>(w_hi, w_lo, lr, lq, sid, half, w3b, b3s, xr, v, c_buf, h2b);
    chunk_body<1>(w_hi, w_lo, lr, lq, sid, half, w3b, b3s, xr, v, c_buf, h2b);
    chunk_body<2>(w_hi, w_lo, lr, lq, sid, half, w3b, b3s, xr, v, c_buf, h2b);
    chunk_body<3>(w_hi, w_lo, lr, lq, sid, half, w3b, b3s, xr, v, c_buf, h2b);
    chunk_body<4>(w_hi, w_lo, lr, lq, sid, half, w3b, b3s, xr, v, c_buf, h2b);
    chunk_body<5>(w_hi, w_lo, lr, lq, sid, half, w3b, b3s, xr, v, c_buf, h2b);
    chunk_body<6>(w_hi, w_lo, lr, lq, sid, half, w3b, b3s, xr, v, c_buf, h2b);
    chunk_body<7>(w_hi, w_lo, lr, lq, sid, half, w3b, b3s, xr, v, c_buf, h2b);
    chunk_body<8>(w_hi, w_lo, lr, lq, sid, half, w3b, b3s, xr, v, c_buf, h2b);
    chunk_body<9>(w_hi, w_lo, lr, lq, sid, half, w3b, b3s, xr, v, c_buf, h2b);

    float acc_y = 0.f;
    #pragma unroll
    for (int q = 0; q < 12; ++q) acc_y = fmaf(v[q], v[q], acc_y);

    if (half == 1) yb[sid] = acc_y;
    __syncthreads();
    if (half == 0) y[sbase + sid] = LN2SQ * (acc_y + yb[sid]);
}

extern "C" void kernel_launch(void* const* d_in, const int* in_sizes, int n_in,
                              void* d_out, int out_size, void* d_ws, size_t ws_size,
                              hipStream_t stream) {
    const float* x  = (const float*)d_in[0];
    const float* W1 = (const float*)d_in[1];
    const float* b1 = (const float*)d_in[2];
    const float* W2 = (const float*)d_in[3];
    const float* b2 = (const float*)d_in[4];
    const float* W3 = (const float*)d_in[5];
    const float* b3 = (const float*)d_in[6];
    float* y = (float*)d_out;

    unsigned short* ws = (unsigned short*)d_ws;      // 37056 B used
    const unsigned short* w1b = ws;
    const unsigned short* w2b = ws + 4096;
    const unsigned short* w3b = ws + 8192;
    const float* b3s = reinterpret_cast<const float*>(ws + 17920);

    const int B = in_sizes[0] / NI;   // 131072, divisible by SPB
    const int cvt_elems = 8192 + W3R * H2 + W3R;
    wcvt<<<dim3((cvt_elems + 255) / 256), dim3(256), 0, stream>>>(W1, W2, W3, b3, ws);
    qnet_fused<<<dim3(B / SPB), dim3(256), 0, stream>>>(
        x, w1b, b1, w2b, b2, w3b, b3s, y, B);
}

// Round 15
// 34.439 us; speedup vs baseline: 1.1942x; 1.0323x over previous
//
#include <hip/hip_runtime.h>
#include <hip/hip_bf16.h>
#include <math.h>

// QuadraticNetCholesky fused kernel, round 15 = R14 (proven 35.5us) with ONE
// change: softplus's log2 replaced by a cubic polynomial in p = 2^-|z'|
// (P(p) = p(a + p(b + pc)), a=log2e exact slope at 0, through (1,1); max err
// ~4e-3 log2-units -> delta-y ~ 3 << headroom). Rationale: trans-pipe budget
// is ~20us/CU (760 trans/sample x 8cyc) and measured dur ~ trans+VALU SUM ->
// trans blocks the VALU issue slot; swapping 8-cyc log2 for 6-cyc of fma
// saves ~4us if that model is right. Isolated A/B on the best-known base.

constexpr int NI  = 24;
constexpr int H1  = 128;
constexpr int H2  = 32;
constexpr int SPB = 128;     // samples per block (256 threads, 4 waves)
constexpr int NT_TOT = 19;   // ceil(300/16) W3 row tiles
constexpr int W3R = 304;
constexpr float LOG2E = 1.4426950408889634f;
constexpr float LN2SQ = 0.4804530139182014f;   // ln(2)^2

typedef __attribute__((ext_vector_type(8))) short bf16x8;
typedef __attribute__((ext_vector_type(4))) float f32x4;

__device__ __forceinline__ float elu_f(float v) {
    return v > 0.0f ? v : __expf(v) - 1.0f;
}
__device__ __forceinline__ float exp2_hw(float x) {
    float r; asm("v_exp_f32 %0, %1" : "=v"(r) : "v"(x)); return r;
}
// softplus(z)/ln2 with z' = z*log2e: max(z',0) + P(2^-|z'|),
// P(p) ~= log2(1+p) cubic, exact at p=0 (slope log2e) and p=1 (value 1).
__device__ __forceinline__ float softplus_g(float zp) {
    float p = exp2_hw(-fabsf(zp));
    float t = fmaf(p, 0.205690f, -0.648385f);
    t = fmaf(p, t, 1.4426950f);
    return fmaxf(zp, 0.0f) + p * t;
}
__device__ __forceinline__ unsigned short f2bf(float f) {
    return __builtin_bit_cast(unsigned short, __float2bfloat16(f));
}
__device__ __forceinline__ unsigned int pk2(float a, float b) {
    return (unsigned int)f2bf(a) | ((unsigned int)f2bf(b) << 16);
}

// ---- prologue: bf16 weight tables in d_ws ----
// shorts: w1b [128][32] @0 (K-pad 24->32 zeros); w2b [32][128] @4096;
//         w3b [304][32] @8192 (pre-scaled by log2e); b3s f32[304] @short 17920.
__global__ void wcvt(const float* __restrict__ W1, const float* __restrict__ W2,
                     const float* __restrict__ W3, const float* __restrict__ b3,
                     unsigned short* __restrict__ ws) {
    int idx = blockIdx.x * 256 + threadIdx.x;
    if (idx < 4096) {
        int n = idx >> 5, k = idx & 31;
        ws[idx] = f2bf(k < NI ? W1[n * NI + k] : 0.0f);
    } else if (idx < 8192) {
        ws[idx] = f2bf(W2[idx - 4096]);
    } else if (idx < 8192 + W3R * H2) {
        int j = idx - 8192;
        int t = j >> 5;
        ws[idx] = f2bf(t < 300 ? W3[j] * LOG2E : 0.0f);
    } else if (idx < 8192 + W3R * H2 + W3R) {
        int t = idx - (8192 + W3R * H2);
        float* b3s = reinterpret_cast<float*>(ws + 17920);
        b3s[t] = (t < 300) ? b3[t] * LOG2E : 0.0f;
    }
}

// compile-time-pruned v accumulation over window [C0, C0+32)
template<int J0, int C0>
__device__ __forceinline__ void vaccum(const float xr[NI], float v[12],
                                       const float* __restrict__ crow) {
    #pragma unroll
    for (int q = 0; q < 12; ++q) {
        const int j = 2 * q + J0;
        #pragma unroll
        for (int i = j; i < NI; ++i) {
            const int t = i * (i + 1) / 2 + j;
            if (t >= C0 && t < C0 + 32)
                v[q] = fmaf(xr[i], crow[t - C0], v[q]);
        }
    }
}

template<int CH>
__device__ __forceinline__ void chunk_body(
    int w_hi, int w_lo, int lr, int lq, int sid, int half,
    const unsigned short* __restrict__ w3b, const float* __restrict__ b3s,
    const float xr[NI], float v[12],
    float* __restrict__ c_buf, const unsigned short* __restrict__ h2b)
{
    const int my_nt = 2 * CH + w_hi;          // wave-uniform N-tile
    if (my_nt < NT_TOT) {
        const int t = my_nt * 16 + lr;
        bf16x8 wf = *reinterpret_cast<const bf16x8*>(w3b + t * H2 + lq * 8);
        const float bias = b3s[t];
        #pragma unroll
        for (int q = 0; q < 4; ++q) {
            const int st = 4 * w_lo + q;
            bf16x8 hb = *reinterpret_cast<const bf16x8*>(h2b + (st * 16 + lr) * 40 + lq * 8);
            f32x4 a = {0.f, 0.f, 0.f, 0.f};
            a = __builtin_amdgcn_mfma_f32_16x16x32_bf16(hb, wf, a, 0, 0, 0);
            // C: col(lane&15)=t-in-tile, row(4lq+r)=sample-in-st-tile
            #pragma unroll
            for (int r = 0; r < 4; ++r) {
                float g = softplus_g(a[r] + bias);
                c_buf[(st * 16 + 4 * lq + r) * 33 + (my_nt & 1) * 16 + lr] = g;
            }
        }
    }
    __syncthreads();
    if (half == 0) vaccum<1, CH * 32>(xr, v, c_buf + sid * 33);   // odd j
    else           vaccum<0, CH * 32>(xr, v, c_buf + sid * 33);   // even j
    __syncthreads();
}

__global__ __launch_bounds__(256, 4) void qnet_fused(
    const float* __restrict__ x,
    const unsigned short* __restrict__ w1b, const float* __restrict__ b1,
    const unsigned short* __restrict__ w2b, const float* __restrict__ b2,
    const unsigned short* __restrict__ w3b, const float* __restrict__ b3s,
    float* __restrict__ y, int B)
{
    // Layout (bytes): xb [128][40]sh @0..10240 ; h1s [128][40]sh @10240..20480 ;
    // h2b [128][40]sh @20480..30720 ; overlays on dead xb+h1s after stage 2:
    // c_buf [128][33]f32 @0..16896 ; yb f32[128] @16896..17408.
    __shared__ __align__(16) unsigned char L[30720];
    unsigned short* xb  = reinterpret_cast<unsigned short*>(L);          // [128][40]
    unsigned short* h1s = reinterpret_cast<unsigned short*>(L + 10240);  // [128][40]
    unsigned short* h2b = reinterpret_cast<unsigned short*>(L + 20480);  // [128][40]
    float* c_buf = reinterpret_cast<float*>(L);                          // [128][33] overlay
    float* yb    = reinterpret_cast<float*>(L + 16896);                  // [128] overlay

    const int tid  = threadIdx.x;
    const int sid  = tid & (SPB - 1);
    const int lane = tid & 63;
    const int lr   = lane & 15, lq = lane >> 4;
    const int half = __builtin_amdgcn_readfirstlane(tid >> 7);
    const int wid  = __builtin_amdgcn_readfirstlane(tid >> 6);
    const int w_hi = wid >> 1, w_lo = wid & 1;
    const size_t sbase = (size_t)blockIdx.x * SPB;

    // ---- x: fp32 in regs (for quadratic form) + bf16 once into xb ----
    float xr[NI];
    {
        const float4* xp4 = reinterpret_cast<const float4*>(x + (sbase + sid) * NI);
        #pragma unroll
        for (int q = 0; q < NI / 4; ++q) {
            float4 t4 = xp4[q];
            xr[4*q+0] = t4.x; xr[4*q+1] = t4.y; xr[4*q+2] = t4.z; xr[4*q+3] = t4.w;
        }
    }
    if (half == 0) {
        unsigned int pk[12];
        #pragma unroll
        for (int q = 0; q < 12; ++q) pk[q] = pk2(xr[2*q], xr[2*q+1]);
        uint4* dst = reinterpret_cast<uint4*>(xb + sid * 40);
        dst[0] = make_uint4(pk[0], pk[1], pk[2], pk[3]);
        dst[1] = make_uint4(pk[4], pk[5], pk[6], pk[7]);
        dst[2] = make_uint4(pk[8], pk[9], pk[10], pk[11]);
    } else {
        *reinterpret_cast<uint4*>(xb + sid * 40 + 24) = make_uint4(0, 0, 0, 0);  // K-pad
    }
    __syncthreads();

    // ---- stages 1+2, K-chunked by 32 h1-rows; stage-2 partials in regs ----
    f32x4 acc[2][2];
    #pragma unroll
    for (int u = 0; u < 2; ++u)
        #pragma unroll
        for (int n2 = 0; n2 < 2; ++n2) acc[u][n2] = (f32x4){0.f, 0.f, 0.f, 0.f};

    #pragma unroll
    for (int kk = 0; kk < 4; ++kk) {
        // stage 1: h1 rows [32kk, 32kk+32) for all 128 samples
        const int nt1 = 2 * kk + w_hi;
        bf16x8 af = *reinterpret_cast<const bf16x8*>(w1b + (nt1 * 16 + lr) * 32 + lq * 8);
        const float4 bb1 = *reinterpret_cast<const float4*>(b1 + nt1 * 16 + 4 * lq);
        #pragma unroll
        for (int q = 0; q < 4; ++q) {
            const int st = 4 * w_lo + q;
            bf16x8 bf = *reinterpret_cast<const bf16x8*>(xb + (st * 16 + lr) * 40 + lq * 8);
            f32x4 a = {0.f, 0.f, 0.f, 0.f};
            a = __builtin_amdgcn_mfma_f32_16x16x32_bf16(af, bf, a, 0, 0, 0);
            unsigned int p0 = pk2(elu_f(a[0] + bb1.x), elu_f(a[1] + bb1.y));
            unsigned int p1 = pk2(elu_f(a[2] + bb1.z), elu_f(a[3] + bb1.w));
            unsigned long long pw = (unsigned long long)p0 | ((unsigned long long)p1 << 32);
            // sample = st*16+lr; local col = w_hi*16 + 4lq + r
            *reinterpret_cast<unsigned long long*>(
                h1s + (st * 16 + lr) * 40 + w_hi * 16 + 4 * lq) = pw;
        }
        __syncthreads();
        // stage 2: accumulate this K-chunk into register C-tiles
        #pragma unroll
        for (int u = 0; u < 2; ++u) {
            const int st2 = 2 * wid + u;
            bf16x8 hb = *reinterpret_cast<const bf16x8*>(h1s + (st2 * 16 + lr) * 40 + lq * 8);
            #pragma unroll
            for (int n2 = 0; n2 < 2; ++n2) {
                bf16x8 wf = *reinterpret_cast<const bf16x8*>(
                    w2b + (n2 * 16 + lr) * H1 + kk * 32 + lq * 8);
                acc[u][n2] = __builtin_amdgcn_mfma_f32_16x16x32_bf16(wf, hb, acc[u][n2], 0, 0, 0);
            }
        }
        __syncthreads();
    }

    // ---- finish h2: elu + bias, pack bf16 to h2b ----
    #pragma unroll
    for (int u = 0; u < 2; ++u) {
        const int st2 = 2 * wid + u;
        #pragma unroll
        for (int n2 = 0; n2 < 2; ++n2) {
            const float4 bb2 = *reinterpret_cast<const float4*>(b2 + n2 * 16 + 4 * lq);
            unsigned int p0 = pk2(elu_f(acc[u][n2][0] + bb2.x), elu_f(acc[u][n2][1] + bb2.y));
            unsigned int p1 = pk2(elu_f(acc[u][n2][2] + bb2.z), elu_f(acc[u][n2][3] + bb2.w));
            unsigned long long pw = (unsigned long long)p0 | ((unsigned long long)p1 << 32);
            // sample = st2*16+lr; col = n2*16 + 4lq + r
            *reinterpret_cast<unsigned long long*>(
                h2b + (st2 * 16 + lr) * 40 + n2 * 16 + 4 * lq) = pw;
        }
    }
    __syncthreads();   // h2b ready; xb/h1s dead -> region becomes c_buf

    // ---- stage 3: 10 chunks of 32 tril-cols ----
    float v[12];
    #pragma unroll
    for (int q = 0; q < 12; ++q) v[q] = 0.f;

    chunk_body<0>(w_hi, w_lo, lr, lq, sid, half, w3b, b3s, xr, v, c_buf, h2b);
    chunk_body<1>(w_hi, w_lo, lr, lq, sid, half, w3b, b3s, xr, v, c_buf, h2b);
    chunk_body<2>(w_hi, w_lo, lr, lq, sid, half, w3b, b3s, xr, v, c_buf, h2b);
    chunk_body<3>(w_hi, w_lo, lr, lq, sid, half, w3b, b3s, xr, v, c_buf, h2b);
    chunk_body<4>(w_hi, w_lo, lr, lq, sid, half, w3b, b3s, xr, v, c_buf, h2b);
    chunk_body<5>(w_hi, w_lo, lr, lq, sid, half, w3b, b3s, xr, v, c_buf, h2b);
    chunk_body<6>(w_hi, w_lo, lr, lq, sid, half, w3b, b3s, xr, v, c_buf, h2b);
    chunk_body<7>(w_hi, w_lo, lr, lq, sid, half, w3b, b3s, xr, v, c_buf, h2b);
    chunk_body<8>(w_hi, w_lo, lr, lq, sid, half, w3b, b3s, xr, v, c_buf, h2b);
    chunk_body<9>(w_hi, w_lo, lr, lq, sid, half, w3b, b3s, xr, v, c_buf, h2b);

    float acc_y = 0.f;
    #pragma unroll
    for (int q = 0; q < 12; ++q) acc_y = fmaf(v[q], v[q], acc_y);

    if (half == 1) yb[sid] = acc_y;
    __syncthreads();
    if (half == 0) y[sbase + sid] = LN2SQ * (acc_y + yb[sid]);
}

extern "C" void kernel_launch(void* const* d_in, const int* in_sizes, int n_in,
                              void* d_out, int out_size, void* d_ws, size_t ws_size,
                              hipStream_t stream) {
    const float* x  = (const float*)d_in[0];
    const float* W1 = (const float*)d_in[1];
    const float* b1 = (const float*)d_in[2];
    const float* W2 = (const float*)d_in[3];
    const float* b2 = (const float*)d_in[4];
    const float* W3 = (const float*)d_in[5];
    const float* b3 = (const float*)d_in[6];
    float* y = (float*)d_out;

    unsigned short* ws = (unsigned short*)d_ws;      // 37056 B used
    const unsigned short* w1b = ws;
    const unsigned short* w2b = ws + 4096;
    const unsigned short* w3b = ws + 8192;
    const float* b3s = reinterpret_cast<const float*>(ws + 17920);

    const int B = in_sizes[0] / NI;   // 131072, divisible by SPB
    const int cvt_elems = 8192 + W3R * H2 + W3R;
    wcvt<<<dim3((cvt_elems + 255) / 256), dim3(256), 0, stream>>>(W1, W2, W3, b3, ws);
    qnet_fused<<<dim3(B / SPB), dim3(256), 0, stream>>>(
        x, w1b, b1, w2b, b2, w3b, b3s, y, B);
}